// Round 10
// baseline (98.013 us; speedup 1.0000x reference)
//
#include <hip/hip_runtime.h>
#include <math.h>

// Problem constants (from reference)
#define B_    64
#define N_    2048
#define D_    512
#define C_    128
#define TOPK_ 8
#define LN_EPS_ 1e-5f

// ============================================================================
// MEASUREMENT ROUND: kernels are EXACTLY R7 (best: 52.1 us). The score kernel
// is launched 3x (idempotent: writes score[] deterministically and zeroes
// out[]). dur = 52.1 + 2*(score_stage_cost) -> isolates the score/tail/launch
// decomposition that 4 rounds of cross-round subtraction failed to pin down.
// ============================================================================

// ---------------------------------------------------------------------------
// Kernel 1 (score, 8192 blocks x 256): block = 16 consecutive clips of one
// batch. Self-contained:
//   - blocks 0..31 zero out[] (before any exit; tail accumulates atomically)
//   - per-block validity from the block's OWN 16 mask entries (prefix mask:
//     valid_s[0]==false => whole block invalid -> early exit, no x/W reads)
//   - cw[d] = ln_w[d]*W[d,y_b] staged into LDS; su/cb via wave-shfl + combine
//   - scoring: one clip per 16-lane group (4 clips/wave), 8 float4 x-loads
//     per group, fused sum/sumsq/dot, 4-round butterfly (off 1,2,4,8)
// Mask layout auto-detected via first word (mask[0..7] all-true since
// lengths >= TOPK): 1 -> int32, 0x01010101 -> bytes, else -> float.
// ---------------------------------------------------------------------------
__global__ __launch_bounds__(256) void score_kernel(
    const float* __restrict__ x, const float* __restrict__ ln_w,
    const float* __restrict__ ln_b, const float* __restrict__ W,
    const float* __restrict__ bias, const unsigned char* __restrict__ mask,
    const int* __restrict__ y, float* __restrict__ score,
    float* __restrict__ out) {
  const int t = threadIdx.x;
  const int wave = t >> 6;
  const int lane = t & 63;
  const int lg = lane & 15;                 // lane within 16-group
  const int g  = lane >> 4;                 // clip within wave (0..3)
  const int blk_clip0 = blockIdx.x * 16;
  const int b = blk_clip0 >> 11;            // clip / N_

  __shared__ float4 cw_s[D_ / 4];           // 2 KB
  __shared__ int    valid_s[16];
  __shared__ float  part[4][2];

  // zero out[] (8192 floats) across blocks 0..31 — before any early exit
  if (blockIdx.x < 32) out[blockIdx.x * 256 + t] = 0.f;

  // validity of this block's 16 clips (3 layouts, tag is a broadcast load)
  unsigned int tag = *(const unsigned int*)mask;
  if (t < 16) {
    int clip = blk_clip0 + t;
    int v;
    if (tag == 1u)               v = ((const int*)mask)[clip] != 0;
    else if (tag == 0x01010101u) v = mask[clip] != 0;
    else                         v = ((const float*)mask)[clip] != 0.f;
    valid_s[t] = v;
  }
  __syncthreads();

  if (!valid_s[0]) {                        // prefix mask => all 16 invalid
    if (t < 16) score[blk_clip0 + t] = -INFINITY;
    return;
  }

  // stage cw = ln_w * W[:, y_b] into LDS; accumulate cb/su partials
  int cls = y[b];
  float l0 = 0.f, l1 = 0.f;
  for (int d = t; d < D_; d += 256) {
    float wcol = W[d * C_ + cls];           // strided 512B, L2-hot per batch
    float u = ln_w[d] * wcol;
    ((float*)cw_s)[d] = u;
    l0 += ln_b[d] * wcol;
    l1 += u;
  }
  #pragma unroll
  for (int off = 32; off > 0; off >>= 1) {
    l0 += __shfl_xor(l0, off);
    l1 += __shfl_xor(l1, off);
  }
  if (lane == 0) { part[wave][0] = l0; part[wave][1] = l1; }
  __syncthreads();
  float cb_b = part[0][0] + part[1][0] + part[2][0] + part[3][0] + bias[cls];
  float su_b = part[0][1] + part[1][1] + part[2][1] + part[3][1];

  // score this wave's 4 clips (one per 16-lane group)
  int cgc = blk_clip0 + wave * 4 + g;       // this group's clip
  const float4* xg = (const float4*)(x + (size_t)cgc * D_);
  float4 xv[8];
  #pragma unroll
  for (int j = 0; j < 8; ++j) xv[j] = xg[j * 16 + lg];   // 8 indep loads

  float s = 0.f, sq = 0.f, dt = 0.f;
  #pragma unroll
  for (int j = 0; j < 8; ++j) {
    float4 u = cw_s[j * 16 + lg];
    float4 a = xv[j];
    s  += a.x + a.y + a.z + a.w;
    sq  = fmaf(a.x, a.x, fmaf(a.y, a.y, fmaf(a.z, a.z, fmaf(a.w, a.w, sq))));
    dt  = fmaf(a.x, u.x, fmaf(a.y, u.y, fmaf(a.z, u.z, fmaf(a.w, u.w, dt))));
  }
  #pragma unroll
  for (int off = 1; off < 16; off <<= 1) {  // 4 rounds x 3 = 12 shfl
    s  += __shfl_xor(s,  off);
    sq += __shfl_xor(sq, off);
    dt += __shfl_xor(dt, off);
  }
  if (lg == 0) {
    float mu = s * (1.f / D_);
    float var = sq * (1.f / D_) - mu * mu;
    float rstd = rsqrtf(var + LN_EPS_);
    float val = rstd * (dt - mu * su_b) + cb_b;
    score[cgc] = valid_s[wave * 4 + g] ? val : -INFINITY;
  }
}

// ---------------------------------------------------------------------------
// Kernel 2 (tail): 512 blocks x 128 threads; block (b,k). Unchanged from R7.
// ---------------------------------------------------------------------------
__global__ __launch_bounds__(128) void tail_kernel(
    const float* __restrict__ x, const float* __restrict__ ln_w,
    const float* __restrict__ ln_b, const float* __restrict__ W,
    const float* __restrict__ bias, const float* __restrict__ score,
    float* __restrict__ out) {
  int b = blockIdx.x >> 3;
  int k = blockIdx.x & 7;
  int t = threadIdx.x;
  int lane = t & 63;

  __shared__ int   top_s[TOPK_];
  __shared__ float xn_s[D_];               // 2 KB
  __shared__ float red_s[2][2];

  // ---- top-8 of batch b (wave 0 only; ties -> smaller index) ----
  if (t < 64) {
    float v[32];
    #pragma unroll
    for (int j = 0; j < 32; ++j) v[j] = score[b * N_ + j * 64 + lane];
    for (int k2 = 0; k2 < TOPK_; ++k2) {
      float bv = -INFINITY;
      int bi = N_;
      #pragma unroll
      for (int j = 0; j < 32; ++j) {
        int e = j * 64 + lane;
        if (v[j] > bv || (v[j] == bv && e < bi)) { bv = v[j]; bi = e; }
      }
      for (int off = 32; off > 0; off >>= 1) {
        float ov = __shfl_xor(bv, off);
        int   oi = __shfl_xor(bi, off);
        if (ov > bv || (ov == bv && oi < bi)) { bv = ov; bi = oi; }
      }
      if (lane == 0) top_s[k2] = bi;
      if ((bi & 63) == lane) v[bi >> 6] = -INFINITY;   // owner removes it
    }
  }
  __syncthreads();

  // ---- LayerNorm winner k (128 threads, float4) ----
  int n = top_s[k];
  const float4* xp4 = (const float4*)(x + ((size_t)b * N_ + n) * D_);
  float4 xv = xp4[t];
  float s  = xv.x + xv.y + xv.z + xv.w;
  float sq = fmaf(xv.x, xv.x, fmaf(xv.y, xv.y, fmaf(xv.z, xv.z, xv.w * xv.w)));
  for (int off = 32; off > 0; off >>= 1) {
    s  += __shfl_xor(s,  off);
    sq += __shfl_xor(sq, off);
  }
  if (lane == 0) { red_s[t >> 6][0] = s; red_s[t >> 6][1] = sq; }
  __syncthreads();
  float mu   = (red_s[0][0] + red_s[1][0]) * (1.f / D_);
  float var  = (red_s[0][1] + red_s[1][1]) * (1.f / D_) - mu * mu;
  float rstd = rsqrtf(var + LN_EPS_);
  float4 wv = ((const float4*)ln_w)[t];
  float4 bv = ((const float4*)ln_b)[t];
  float4 yv;
  yv.x = fmaf((xv.x - mu) * rstd, wv.x, bv.x);
  yv.y = fmaf((xv.y - mu) * rstd, wv.y, bv.y);
  yv.z = fmaf((xv.z - mu) * rstd, wv.z, bv.z);
  yv.w = fmaf((xv.w - mu) * rstd, wv.w, bv.w);
  ((float4*)xn_s)[t] = yv;
  __syncthreads();

  // ---- dot: thread t = class t; xn via uniform float4 broadcast ----
  float a0 = 0.f, a1 = 0.f, a2 = 0.f, a3 = 0.f;
  #pragma unroll 4
  for (int ch = 0; ch < D_ / 4; ++ch) {
    float4 xn = ((const float4*)xn_s)[ch];           // LDS broadcast
    a0 = fmaf(xn.x, W[(ch * 4 + 0) * C_ + t], a0);   // W coalesced, L2-hot
    a1 = fmaf(xn.y, W[(ch * 4 + 1) * C_ + t], a1);
    a2 = fmaf(xn.z, W[(ch * 4 + 2) * C_ + t], a2);
    a3 = fmaf(xn.w, W[(ch * 4 + 3) * C_ + t], a3);
  }
  float dot = (a0 + a1) + (a2 + a3);
  atomicAdd(&out[b * C_ + t], (dot + bias[t]) * (1.f / TOPK_));
}

// ---------------------------------------------------------------------------
extern "C" void kernel_launch(void* const* d_in, const int* in_sizes, int n_in,
                              void* d_out, int out_size, void* d_ws, size_t ws_size,
                              hipStream_t stream) {
  const float* x    = (const float*)d_in[0];
  const float* ln_w = (const float*)d_in[1];
  const float* ln_b = (const float*)d_in[2];
  const float* W    = (const float*)d_in[3];
  const float* bias = (const float*)d_in[4];
  const unsigned char* mask = (const unsigned char*)d_in[5];
  const int* y      = (const int*)d_in[6];
  float* out = (float*)d_out;

  float* score = (float*)d_ws;                       // 512 KB scratch

  // MEASUREMENT: score launched 3x (idempotent). dur - 52.1 = 2*(S + c).
  score_kernel<<<(B_ * N_) / 16, 256, 0, stream>>>(
      x, ln_w, ln_b, W, bias, mask, y, score, out);
  score_kernel<<<(B_ * N_) / 16, 256, 0, stream>>>(
      x, ln_w, ln_b, W, bias, mask, y, score, out);
  score_kernel<<<(B_ * N_) / 16, 256, 0, stream>>>(
      x, ln_w, ln_b, W, bias, mask, y, score, out);
  tail_kernel <<<B_ * TOPK_, 128, 0, stream>>>(
      x, ln_w, ln_b, W, bias, score, out);
}

// Round 11
// 52.040 us; speedup vs baseline: 1.8834x; 1.8834x over previous
//
#include <hip/hip_runtime.h>
#include <math.h>

// Problem constants (from reference)
#define B_    64
#define N_    2048
#define D_    512
#define C_    128
#define TOPK_ 8
#define LN_EPS_ 1e-5f

// ============================================================================
// FINAL (= R7, best measured: 52.1 us). Two eager nodes:
//   score (8192 blocks): at 93-96% of the 6.3 TB/s stream ceiling (measured
//     marginal stage cost 23.0 us vs 21.4 us floor for ~135 MB of valid x).
//   tail (512 blocks): ~5 us stage (top-8 + LN + class-dot + atomic average).
// Fixed per-replay base ~20-24 us is harness overhead (invariant across all
// structures tried); grid-wide fusion attempts regressed 4-30x (R6/R8).
// ============================================================================

// ---------------------------------------------------------------------------
// Kernel 1 (score): block = 16 consecutive clips of one batch.
//   - blocks 0..31 zero out[] (before any exit; tail accumulates atomically)
//   - per-block validity from the block's OWN 16 mask entries (prefix mask:
//     valid_s[0]==false => whole block invalid -> early exit, no x/W reads)
//   - cw[d] = ln_w[d]*W[d,y_b] staged into LDS; su/cb via wave-shfl + combine
//   - scoring: one clip per 16-lane group (4 clips/wave), 8 float4 x-loads
//     per group, fused sum/sumsq/dot, 4-round butterfly (off 1,2,4,8)
// Mask layout auto-detected via first word (mask[0..7] all-true since
// lengths >= TOPK): 1 -> int32, 0x01010101 -> bytes, else -> float.
// ---------------------------------------------------------------------------
__global__ __launch_bounds__(256) void score_kernel(
    const float* __restrict__ x, const float* __restrict__ ln_w,
    const float* __restrict__ ln_b, const float* __restrict__ W,
    const float* __restrict__ bias, const unsigned char* __restrict__ mask,
    const int* __restrict__ y, float* __restrict__ score,
    float* __restrict__ out) {
  const int t = threadIdx.x;
  const int wave = t >> 6;
  const int lane = t & 63;
  const int lg = lane & 15;                 // lane within 16-group
  const int g  = lane >> 4;                 // clip within wave (0..3)
  const int blk_clip0 = blockIdx.x * 16;
  const int b = blk_clip0 >> 11;            // clip / N_

  __shared__ float4 cw_s[D_ / 4];           // 2 KB
  __shared__ int    valid_s[16];
  __shared__ float  part[4][2];

  // zero out[] (8192 floats) across blocks 0..31 — before any early exit
  if (blockIdx.x < 32) out[blockIdx.x * 256 + t] = 0.f;

  // validity of this block's 16 clips (3 layouts, tag is a broadcast load)
  unsigned int tag = *(const unsigned int*)mask;
  if (t < 16) {
    int clip = blk_clip0 + t;
    int v;
    if (tag == 1u)               v = ((const int*)mask)[clip] != 0;
    else if (tag == 0x01010101u) v = mask[clip] != 0;
    else                         v = ((const float*)mask)[clip] != 0.f;
    valid_s[t] = v;
  }
  __syncthreads();

  if (!valid_s[0]) {                        // prefix mask => all 16 invalid
    if (t < 16) score[blk_clip0 + t] = -INFINITY;
    return;
  }

  // stage cw = ln_w * W[:, y_b] into LDS; accumulate cb/su partials
  int cls = y[b];
  float l0 = 0.f, l1 = 0.f;
  for (int d = t; d < D_; d += 256) {
    float wcol = W[d * C_ + cls];           // strided 512B, L2-hot per batch
    float u = ln_w[d] * wcol;
    ((float*)cw_s)[d] = u;
    l0 += ln_b[d] * wcol;
    l1 += u;
  }
  #pragma unroll
  for (int off = 32; off > 0; off >>= 1) {
    l0 += __shfl_xor(l0, off);
    l1 += __shfl_xor(l1, off);
  }
  if (lane == 0) { part[wave][0] = l0; part[wave][1] = l1; }
  __syncthreads();
  float cb_b = part[0][0] + part[1][0] + part[2][0] + part[3][0] + bias[cls];
  float su_b = part[0][1] + part[1][1] + part[2][1] + part[3][1];

  // score this wave's 4 clips (one per 16-lane group)
  int cgc = blk_clip0 + wave * 4 + g;       // this group's clip
  const float4* xg = (const float4*)(x + (size_t)cgc * D_);
  float4 xv[8];
  #pragma unroll
  for (int j = 0; j < 8; ++j) xv[j] = xg[j * 16 + lg];   // 8 indep loads

  float s = 0.f, sq = 0.f, dt = 0.f;
  #pragma unroll
  for (int j = 0; j < 8; ++j) {
    float4 u = cw_s[j * 16 + lg];
    float4 a = xv[j];
    s  += a.x + a.y + a.z + a.w;
    sq  = fmaf(a.x, a.x, fmaf(a.y, a.y, fmaf(a.z, a.z, fmaf(a.w, a.w, sq))));
    dt  = fmaf(a.x, u.x, fmaf(a.y, u.y, fmaf(a.z, u.z, fmaf(a.w, u.w, dt))));
  }
  #pragma unroll
  for (int off = 1; off < 16; off <<= 1) {  // 4 rounds x 3 = 12 shfl
    s  += __shfl_xor(s,  off);
    sq += __shfl_xor(sq, off);
    dt += __shfl_xor(dt, off);
  }
  if (lg == 0) {
    float mu = s * (1.f / D_);
    float var = sq * (1.f / D_) - mu * mu;
    float rstd = rsqrtf(var + LN_EPS_);
    float val = rstd * (dt - mu * su_b) + cb_b;
    score[cgc] = valid_s[wave * 4 + g] ? val : -INFINITY;
  }
}

// ---------------------------------------------------------------------------
// Kernel 2 (tail): 512 blocks x 128 threads; block (b,k).
// Wave 0 redundantly computes batch b's top-8 (identical across the 8 blocks
// of b -> deterministic; ties -> smaller index = lax.top_k). Then LN of
// winner k, class-dot with uniform float4 LDS broadcasts, atomicAdd average.
// ---------------------------------------------------------------------------
__global__ __launch_bounds__(128) void tail_kernel(
    const float* __restrict__ x, const float* __restrict__ ln_w,
    const float* __restrict__ ln_b, const float* __restrict__ W,
    const float* __restrict__ bias, const float* __restrict__ score,
    float* __restrict__ out) {
  int b = blockIdx.x >> 3;
  int k = blockIdx.x & 7;
  int t = threadIdx.x;
  int lane = t & 63;

  __shared__ int   top_s[TOPK_];
  __shared__ float xn_s[D_];               // 2 KB
  __shared__ float red_s[2][2];

  // ---- top-8 of batch b (wave 0 only; ties -> smaller index) ----
  if (t < 64) {
    float v[32];
    #pragma unroll
    for (int j = 0; j < 32; ++j) v[j] = score[b * N_ + j * 64 + lane];
    for (int k2 = 0; k2 < TOPK_; ++k2) {
      float bv = -INFINITY;
      int bi = N_;
      #pragma unroll
      for (int j = 0; j < 32; ++j) {
        int e = j * 64 + lane;
        if (v[j] > bv || (v[j] == bv && e < bi)) { bv = v[j]; bi = e; }
      }
      for (int off = 32; off > 0; off >>= 1) {
        float ov = __shfl_xor(bv, off);
        int   oi = __shfl_xor(bi, off);
        if (ov > bv || (ov == bv && oi < bi)) { bv = ov; bi = oi; }
      }
      if (lane == 0) top_s[k2] = bi;
      if ((bi & 63) == lane) v[bi >> 6] = -INFINITY;   // owner removes it
    }
  }
  __syncthreads();

  // ---- LayerNorm winner k (128 threads, float4) ----
  int n = top_s[k];
  const float4* xp4 = (const float4*)(x + ((size_t)b * N_ + n) * D_);
  float4 xv = xp4[t];
  float s  = xv.x + xv.y + xv.z + xv.w;
  float sq = fmaf(xv.x, xv.x, fmaf(xv.y, xv.y, fmaf(xv.z, xv.z, xv.w * xv.w)));
  for (int off = 32; off > 0; off >>= 1) {
    s  += __shfl_xor(s,  off);
    sq += __shfl_xor(sq, off);
  }
  if (lane == 0) { red_s[t >> 6][0] = s; red_s[t >> 6][1] = sq; }
  __syncthreads();
  float mu   = (red_s[0][0] + red_s[1][0]) * (1.f / D_);
  float var  = (red_s[0][1] + red_s[1][1]) * (1.f / D_) - mu * mu;
  float rstd = rsqrtf(var + LN_EPS_);
  float4 wv = ((const float4*)ln_w)[t];
  float4 bv = ((const float4*)ln_b)[t];
  float4 yv;
  yv.x = fmaf((xv.x - mu) * rstd, wv.x, bv.x);
  yv.y = fmaf((xv.y - mu) * rstd, wv.y, bv.y);
  yv.z = fmaf((xv.z - mu) * rstd, wv.z, bv.z);
  yv.w = fmaf((xv.w - mu) * rstd, wv.w, bv.w);
  ((float4*)xn_s)[t] = yv;
  __syncthreads();

  // ---- dot: thread t = class t; xn via uniform float4 broadcast ----
  float a0 = 0.f, a1 = 0.f, a2 = 0.f, a3 = 0.f;
  #pragma unroll 4
  for (int ch = 0; ch < D_ / 4; ++ch) {
    float4 xn = ((const float4*)xn_s)[ch];           // LDS broadcast
    a0 = fmaf(xn.x, W[(ch * 4 + 0) * C_ + t], a0);   // W coalesced, L2-hot
    a1 = fmaf(xn.y, W[(ch * 4 + 1) * C_ + t], a1);
    a2 = fmaf(xn.z, W[(ch * 4 + 2) * C_ + t], a2);
    a3 = fmaf(xn.w, W[(ch * 4 + 3) * C_ + t], a3);
  }
  float dot = (a0 + a1) + (a2 + a3);
  atomicAdd(&out[b * C_ + t], (dot + bias[t]) * (1.f / TOPK_));
}

// ---------------------------------------------------------------------------
extern "C" void kernel_launch(void* const* d_in, const int* in_sizes, int n_in,
                              void* d_out, int out_size, void* d_ws, size_t ws_size,
                              hipStream_t stream) {
  const float* x    = (const float*)d_in[0];
  const float* ln_w = (const float*)d_in[1];
  const float* ln_b = (const float*)d_in[2];
  const float* W    = (const float*)d_in[3];
  const float* bias = (const float*)d_in[4];
  const unsigned char* mask = (const unsigned char*)d_in[5];
  const int* y      = (const int*)d_in[6];
  float* out = (float*)d_out;

  float* score = (float*)d_ws;                       // 512 KB scratch

  score_kernel<<<(B_ * N_) / 16, 256, 0, stream>>>(
      x, ln_w, ln_b, W, bias, mask, y, score, out);
  tail_kernel <<<B_ * TOPK_, 128, 0, stream>>>(
      x, ln_w, ln_b, W, bias, score, out);
}